// Round 10
// baseline (46.134 us; speedup 1.0000x reference)
//
#include <hip/hip_runtime.h>

#define B 2
#define S 512
#define D 256
#define C2L 2.885390081777927f    // 2*log2(e)
#define LOG2E 1.4426950408889634f

typedef float f32x2 __attribute__((ext_vector_type(2)));
typedef unsigned int u32x2 __attribute__((ext_vector_type(2)));

// proj: Pt = (q @ W^T) * C2L.
//   EJ4[b][e>>2][i][e&3] = exp2(Pt)  (float4-over-e: score loads dwordx4, coalesced)
//   EN[b][i][e] = exp2(-Pt)          (row-major: fused kernel row factors)
__global__ __launch_bounds__(256) void proj_kernel(const float* __restrict__ q,
                                                   const float* __restrict__ W,
                                                   float* __restrict__ EJ4,
                                                   float* __restrict__ EN) {
    __shared__ float qlds[4 * D];
    const int t = threadIdx.x;
    const int b = blockIdx.x / (S / 4);
    const int i0 = (blockIdx.x % (S / 4)) * 4;
    const float* qbase = q + (size_t)(b * S + i0) * D;
    for (int idx = t; idx < 4 * D; idx += 256) qlds[idx] = qbase[idx];
    __syncthreads();
    const float* wr = W + (size_t)t * D;
    float a0 = 0.f, a1 = 0.f, a2 = 0.f, a3 = 0.f;
#pragma unroll 4
    for (int d = 0; d < D; ++d) {
        float w = wr[d];
        a0 = fmaf(qlds[d], w, a0);
        a1 = fmaf(qlds[D + d], w, a1);
        a2 = fmaf(qlds[2 * D + d], w, a2);
        a3 = fmaf(qlds[3 * D + d], w, a3);
    }
    a0 *= C2L; a1 *= C2L; a2 *= C2L; a3 *= C2L;
    float* ejb = EJ4 + (((size_t)(b * 64 + (t >> 2))) * S + i0) * 4 + (t & 3);
    ejb[0]  = __builtin_amdgcn_exp2f(a0);
    ejb[4]  = __builtin_amdgcn_exp2f(a1);
    ejb[8]  = __builtin_amdgcn_exp2f(a2);
    ejb[12] = __builtin_amdgcn_exp2f(a3);
    EN[(size_t)(b * S + i0 + 0) * D + t] = __builtin_amdgcn_exp2f(-a0);
    EN[(size_t)(b * S + i0 + 1) * D + t] = __builtin_amdgcn_exp2f(-a1);
    EN[(size_t)(b * S + i0 + 2) * D + t] = __builtin_amdgcn_exp2f(-a2);
    EN[(size_t)(b * S + i0 + 3) * D + t] = __builtin_amdgcn_exp2f(-a3);
}

// Fused score + softmax + context. Block = 4 rows, 1024 threads:
// thread (j = t&511, eh = t>>9) computes the e-half partial scores for all 4
// rows; halves combine via LDS. 16 waves/CU = 4 waves/SIMD for latency hiding
// at UNCHANGED global traffic. Softmax/ctx phases run on the lower 512 threads.
__global__ __launch_bounds__(1024) void fused_kernel(const float* __restrict__ EJ4,
                                                     const float* __restrict__ EN,
                                                     const float* __restrict__ vm,
                                                     const float* __restrict__ value,
                                                     float* __restrict__ att,
                                                     float* __restrict__ ctx) {
    __shared__ float en4[D][4];          // comps = rows (i0, i0+2, i0+1, i0+3)
    __shared__ float wl[D];              // -2*vm
    __shared__ float4 comb[2][S];        // e-half partial scores (rows 0..3)
    __shared__ float a4[S][4];           // normalized attention rows
    __shared__ float part[4][8][64][4];  // ctx partials
    __shared__ float redm[4][8], reds[4][8];

    const int t = threadIdx.x;
    const int b = blockIdx.x >> 7;           // S/4 = 128 blocks per batch
    const int i0 = (blockIdx.x & 127) * 4;

    {   // stage row factors: rows (0,2)->comps(0,1) [HW rcp], (1,3)->comps(2,3) [Newton]
        const int e = t & 255, r = t >> 8;
        const int comp = ((r & 1) << 1) | (r >> 1);
        en4[e][comp] = EN[((size_t)(b * S + i0 + r)) * D + e];
        if (r == 0) wl[e] = -2.f * vm[e];
    }
    __syncthreads();

    // ---- score: s'[r] = sum_e (-2 vm_e) * sigma(2(Pj - Pr))  (shift cancels)
    const int j = t & 511, eh = t >> 9;
    f32x2 acc02 = {0.f, 0.f}, acc13 = {0.f, 0.f};
    const float4* ejp = (const float4*)EJ4 + ((size_t)(b * 64 + eh * 32)) * S + j;
    const f32x2 one2 = {1.f, 1.f}, two2 = {2.f, 2.f};
    const u32x2 magic = {0x7EF311C3u, 0x7EF311C3u};
#pragma unroll 8
    for (int g = 0; g < 32; ++g) {
        float4 ev4 = ejp[(size_t)g * S];
#pragma unroll
        for (int c = 0; c < 4; ++c) {
            const float ev = (c == 0) ? ev4.x : (c == 1) ? ev4.y : (c == 2) ? ev4.z : ev4.w;
            const int e = eh * 128 + g * 4 + c;
            float4 f = *(const float4*)&en4[e][0];   // uniform -> LDS broadcast
            const float w = wl[e];
            f32x2 ev2 = {ev, ev};
            f32x2 f02 = {f.x, f.y}, f13 = {f.z, f.w};
            f32x2 y02 = ev2 * f02 + one2;            // v_pk_fma_f32
            f32x2 y13 = ev2 * f13 + one2;
            f32x2 r02 = {__builtin_amdgcn_rcpf(y02.x),
                         __builtin_amdgcn_rcpf(y02.y)};          // trans pipe
            u32x2 ui = magic - __builtin_bit_cast(u32x2, y13);   // VALU pipe
            f32x2 rn = __builtin_bit_cast(f32x2, ui);
            rn = rn * (two2 - y13 * rn);
            rn = rn * (two2 - y13 * rn);
            f32x2 w2 = {w, w};
            acc02 += w2 * r02;
            acc13 += w2 * rn;
        }
    }
    comb[eh][j] = make_float4(acc02.x, acc13.x, acc02.y, acc13.y);  // rows 0..3
    __syncthreads();

    // ---- softmax over j (lower 512 threads; waves 0-7)
    const int lane = t & 63, wv = t >> 6;
    float accR[4], p[4];
    if (t < 512) {
        float4 lo = comb[0][t], hi = comb[1][t];
        accR[0] = lo.x + hi.x; accR[1] = lo.y + hi.y;
        accR[2] = lo.z + hi.z; accR[3] = lo.w + hi.w;
#pragma unroll
        for (int r = 0; r < 4; ++r) {
            float lm = accR[r];
#pragma unroll
            for (int off = 32; off; off >>= 1) lm = fmaxf(lm, __shfl_xor(lm, off));
            if (lane == 0) redm[r][wv] = lm;
        }
    }
    __syncthreads();
    if (t < 512) {
#pragma unroll
        for (int r = 0; r < 4; ++r) {
            float m = redm[r][0];
#pragma unroll
            for (int w = 1; w < 8; ++w) m = fmaxf(m, redm[r][w]);
            p[r] = __builtin_amdgcn_exp2f((accR[r] - m) * LOG2E);
            float ls = p[r];
#pragma unroll
            for (int off = 32; off; off >>= 1) ls += __shfl_xor(ls, off);
            if (lane == 0) reds[r][wv] = ls;
        }
    }
    __syncthreads();
    if (t < 512) {
#pragma unroll
        for (int r = 0; r < 4; ++r) {
            float s = 0.f;
#pragma unroll
            for (int w = 0; w < 8; ++w) s += reds[r][w];
            float a = p[r] * __builtin_amdgcn_rcpf(s);
            a4[t][r] = a;
            att[(size_t)(b * S + i0 + r) * S + t] = a;
        }
    }
    __syncthreads();

    // ---- context: lower 512 threads -> (dq = t&63, js = t>>6)
    if (t < 512) {
        const int dq = t & 63, js = t >> 6;
        float4 acc0 = {}, acc1 = {}, acc2 = {}, acc3 = {};
        const float* vb = value + (size_t)b * S * D + (size_t)dq * 4;
#pragma unroll 4
        for (int jj = 0; jj < 64; ++jj) {
            int jx = js * 64 + jj;
            float4 v = *(const float4*)(vb + (size_t)jx * D);
            float w0 = a4[jx][0], w1 = a4[jx][1], w2 = a4[jx][2], w3 = a4[jx][3];
            acc0.x = fmaf(w0, v.x, acc0.x); acc0.y = fmaf(w0, v.y, acc0.y);
            acc0.z = fmaf(w0, v.z, acc0.z); acc0.w = fmaf(w0, v.w, acc0.w);
            acc1.x = fmaf(w1, v.x, acc1.x); acc1.y = fmaf(w1, v.y, acc1.y);
            acc1.z = fmaf(w1, v.z, acc1.z); acc1.w = fmaf(w1, v.w, acc1.w);
            acc2.x = fmaf(w2, v.x, acc2.x); acc2.y = fmaf(w2, v.y, acc2.y);
            acc2.z = fmaf(w2, v.z, acc2.z); acc2.w = fmaf(w2, v.w, acc2.w);
            acc3.x = fmaf(w3, v.x, acc3.x); acc3.y = fmaf(w3, v.y, acc3.y);
            acc3.z = fmaf(w3, v.z, acc3.z); acc3.w = fmaf(w3, v.w, acc3.w);
        }
        *(float4*)&part[0][js][dq][0] = acc0;
        *(float4*)&part[1][js][dq][0] = acc1;
        *(float4*)&part[2][js][dq][0] = acc2;
        *(float4*)&part[3][js][dq][0] = acc3;
    }
    __syncthreads();
    if (t < 256) {
        const int row = t >> 6, dq = t & 63;
        float4 sum = {};
#pragma unroll
        for (int js = 0; js < 8; ++js) {
            float4 pt = *(const float4*)&part[row][js][dq][0];
            sum.x += pt.x; sum.y += pt.y; sum.z += pt.z; sum.w += pt.w;
        }
        *(float4*)(ctx + (size_t)(b * S + i0 + row) * D + (size_t)dq * 4) = sum;
    }
}

extern "C" void kernel_launch(void* const* d_in, const int* in_sizes, int n_in,
                              void* d_out, int out_size, void* d_ws, size_t ws_size,
                              hipStream_t stream) {
    const float* q = (const float*)d_in[0];
    // d_in[1] = key (unused by the reference)
    const float* value = (const float*)d_in[2];
    const float* W = (const float*)d_in[3];
    const float* vm = (const float*)d_in[4];

    float* ctx = (float*)d_out;                    // [B,S,D]
    float* att = ctx + (size_t)B * S * D;          // [B,S,S]
    float* EJ4 = (float*)d_ws;                     // [B][64][S][4] exp2(Pt), 1 MB
    float* EN = EJ4 + (size_t)B * D * S;           // [B,S,D] exp2(-Pt), 1 MB

    proj_kernel<<<B * (S / 4), 256, 0, stream>>>(q, W, EJ4, EN);
    fused_kernel<<<B * (S / 4), 1024, 0, stream>>>(EJ4, EN, vm, value, att, ctx);
}